// Round 1
// baseline (2445.778 us; speedup 1.0000x reference)
//
#include <hip/hip_runtime.h>
#include <hip/hip_bf16.h>
#include <math.h>

#define BB 16
#define NN 1024
#define CC 384
#define HEADS 4
#define HD 96
#define HID 1536
#define MROWS (BB*NN)
#define QT 8

__device__ __forceinline__ float hswish(float x) {
    float t = fminf(fmaxf(x + 3.0f, 0.0f), 6.0f);
    return x * t * (1.0f / 6.0f);
}

// ---------------- LayerNorm: one wave (64 lanes) per row of 384 ----------------
__global__ __launch_bounds__(256) void ln_kernel(
    const float* __restrict__ x, const float* __restrict__ g,
    const float* __restrict__ b, float* __restrict__ y)
{
    int row = blockIdx.x * 4 + (threadIdx.x >> 6);
    int lane = threadIdx.x & 63;
    const float* xr = x + (size_t)row * CC;
    float v[6];
    float s = 0.f;
#pragma unroll
    for (int j = 0; j < 6; ++j) { v[j] = xr[lane + 64 * j]; s += v[j]; }
#pragma unroll
    for (int off = 32; off; off >>= 1) s += __shfl_xor(s, off, 64);
    float mu = s * (1.0f / CC);
    float s2 = 0.f;
#pragma unroll
    for (int j = 0; j < 6; ++j) { float d = v[j] - mu; s2 += d * d; }
#pragma unroll
    for (int off = 32; off; off >>= 1) s2 += __shfl_xor(s2, off, 64);
    float rinv = rsqrtf(s2 * (1.0f / CC) + 1e-5f);
    float* yr = y + (size_t)row * CC;
#pragma unroll
    for (int j = 0; j < 6; ++j) {
        int c = lane + 64 * j;
        yr[c] = (v[j] - mu) * rinv * g[c] + b[c];
    }
}

// ---------------- GEMM: C[M,N] = A[M,K] @ B[N,K]^T (+bias, +act, +res) --------
// 64x64 tile, BK=16, 256 threads, 4x4 per thread. All dims divide evenly here.
__global__ __launch_bounds__(256) void gemm_bt(
    const float* __restrict__ A, const float* __restrict__ Bm,
    const float* __restrict__ bias, const float* __restrict__ res,
    float* __restrict__ C, int M, int N, int K, int act)
{
    __shared__ float As[16][65];
    __shared__ float Bs[16][65];
    int tid = threadIdx.x;
    int tx = tid & 15, ty = tid >> 4;
    int m0 = blockIdx.y * 64, n0 = blockIdx.x * 64;
    int lr = tid >> 2;          // 0..63: row within tile
    int lk = (tid & 3) * 4;     // 0,4,8,12: k within tile
    float acc[4][4] = {};
    for (int k0 = 0; k0 < K; k0 += 16) {
        float4 a4 = *(const float4*)(A + (size_t)(m0 + lr) * K + k0 + lk);
        float4 b4 = *(const float4*)(Bm + (size_t)(n0 + lr) * K + k0 + lk);
        __syncthreads();
        As[lk + 0][lr] = a4.x; As[lk + 1][lr] = a4.y;
        As[lk + 2][lr] = a4.z; As[lk + 3][lr] = a4.w;
        Bs[lk + 0][lr] = b4.x; Bs[lk + 1][lr] = b4.y;
        Bs[lk + 2][lr] = b4.z; Bs[lk + 3][lr] = b4.w;
        __syncthreads();
#pragma unroll
        for (int k = 0; k < 16; ++k) {
            float a[4], bv[4];
#pragma unroll
            for (int i = 0; i < 4; ++i) { a[i] = As[k][ty * 4 + i]; bv[i] = Bs[k][tx * 4 + i]; }
#pragma unroll
            for (int i = 0; i < 4; ++i)
#pragma unroll
                for (int j = 0; j < 4; ++j) acc[i][j] = fmaf(a[i], bv[j], acc[i][j]);
        }
    }
#pragma unroll
    for (int i = 0; i < 4; ++i) {
        int row = m0 + ty * 4 + i;
#pragma unroll
        for (int j = 0; j < 4; ++j) {
            int col = n0 + tx * 4 + j;
            float v = acc[i][j];
            if (bias) v += bias[col];
            if (act == 1) v = hswish(v);
            if (res) v += res[(size_t)row * N + col];
            C[(size_t)row * N + col] = v;
        }
    }
}

// ---------------- block reduce helper (256 threads = 4 waves) ----------------
__device__ __forceinline__ float blk_red(float v, float* red, int ismax) {
#pragma unroll
    for (int off = 32; off; off >>= 1) {
        float t = __shfl_xor(v, off, 64);
        v = ismax ? fmaxf(v, t) : (v + t);
    }
    __syncthreads();   // protect red from previous call
    if ((threadIdx.x & 63) == 0) red[threadIdx.x >> 6] = v;
    __syncthreads();
    return ismax ? fmaxf(fmaxf(red[0], red[1]), fmaxf(red[2], red[3]))
                 : (red[0] + red[1]) + (red[2] + red[3]);
}

// ---------------- attention: block per (b, head, 8-query tile) ----------------
// qkv row layout per token: [head][{q,k,v}][96]  (stride 3*CC = 1152)
__global__ __launch_bounds__(256) void attn_kernel(
    const float* __restrict__ qkv, float* __restrict__ o)
{
    __shared__ float s[QT][NN];       // 32 KiB scores
    __shared__ float qs[QT][HD];
    __shared__ float red[4];
    int tid = threadIdx.x;
    int b = blockIdx.z, head = blockIdx.y, q0 = blockIdx.x * QT;
    const int rowstride = 3 * CC;
    const float* base = qkv + (size_t)b * NN * rowstride + head * (3 * HD);

    for (int i = tid; i < QT * HD; i += 256) {
        int q = i / HD, d = i % HD;
        qs[q][d] = base[(size_t)(q0 + q) * rowstride + d];
    }
    __syncthreads();

    const float scale = 0.10206207261596577f;  // 96^-0.5
    for (int mi = 0; mi < NN / 256; ++mi) {
        int m = mi * 256 + tid;
        const float* krow = base + (size_t)m * rowstride + HD;
        float acc[QT] = {};
        for (int d = 0; d < HD; ++d) {
            float kv = krow[d];
#pragma unroll
            for (int q = 0; q < QT; ++q) acc[q] = fmaf(qs[q][d], kv, acc[q]);
        }
#pragma unroll
        for (int q = 0; q < QT; ++q) s[q][m] = acc[q] * scale;
    }
    __syncthreads();

    float inv[QT];
    for (int q = 0; q < QT; ++q) {
        float mx = -1e30f;
        for (int m = tid; m < NN; m += 256) mx = fmaxf(mx, s[q][m]);
        mx = blk_red(mx, red, 1);
        float sum = 0.f;
        for (int m = tid; m < NN; m += 256) {
            float p = __expf(s[q][m] - mx);
            s[q][m] = p;
            sum += p;
        }
        sum = blk_red(sum, red, 0);
        inv[q] = 1.0f / sum;
    }
    __syncthreads();

    if (tid < HD) {
        int d = tid;
        const float* vcol = base + 2 * HD + d;
        float oacc[QT] = {};
        for (int m = 0; m < NN; ++m) {
            float vv = vcol[(size_t)m * rowstride];
#pragma unroll
            for (int q = 0; q < QT; ++q) oacc[q] = fmaf(s[q][m], vv, oacc[q]);
        }
#pragma unroll
        for (int q = 0; q < QT; ++q)
            o[(size_t)(b * NN + q0 + q) * CC + head * HD + d] = oacc[q] * inv[q];
    }
}

// ---------------- depthwise 3x3 conv over 32x32 spatial, 1536 channels -------
__global__ __launch_bounds__(256) void dw_kernel(
    const float* __restrict__ h1, const float* __restrict__ w,
    const float* __restrict__ bias, float* __restrict__ h2)
{
    int blk = blockIdx.x;
    int b = blk >> 10;
    int n = blk & 1023;
    int hh = n >> 5, ww = n & 31;
    const float* in = h1 + (size_t)b * NN * HID;
    float* outr = h2 + ((size_t)b * NN + n) * HID;
    for (int c = threadIdx.x; c < HID; c += 256) {
        float acc = bias[c];
#pragma unroll
        for (int ky = 0; ky < 3; ++ky) {
            int yy = hh + ky - 1;
            if (yy < 0 || yy > 31) continue;
#pragma unroll
            for (int kx = 0; kx < 3; ++kx) {
                int xx = ww + kx - 1;
                if (xx < 0 || xx > 31) continue;
                acc = fmaf(in[(size_t)(yy * 32 + xx) * HID + c], w[c * 9 + ky * 3 + kx], acc);
            }
        }
        outr[c] = hswish(acc);
    }
}

extern "C" void kernel_launch(void* const* d_in, const int* in_sizes, int n_in,
                              void* d_out, int out_size, void* d_ws, size_t ws_size,
                              hipStream_t stream) {
    const float* x     = (const float*)d_in[0];
    const float* ln1_g = (const float*)d_in[1];
    const float* ln1_b = (const float*)d_in[2];
    const float* Wqkv  = (const float*)d_in[3];
    const float* Wproj = (const float*)d_in[4];
    const float* bproj = (const float*)d_in[5];
    const float* ln2_g = (const float*)d_in[6];
    const float* ln2_b = (const float*)d_in[7];
    const float* Wfc1  = (const float*)d_in[8];
    const float* bfc1  = (const float*)d_in[9];
    const float* Wdw   = (const float*)d_in[10];
    const float* bdw   = (const float*)d_in[11];
    const float* Wfc2  = (const float*)d_in[12];
    const float* bfc2  = (const float*)d_in[13];
    float* out = (float*)d_out;
    float* buf0 = (float*)d_ws;                       // M x 1536
    float* buf1 = buf0 + (size_t)MROWS * HID;         // M x 1536

    const int M = MROWS;

    // 1. LN1: x -> buf1 (xn)
    ln_kernel<<<M / 4, 256, 0, stream>>>(x, ln1_g, ln1_b, buf1);
    // 2. qkv = xn @ Wqkv^T -> buf0  [M,1152]
    gemm_bt<<<dim3(1152 / 64, M / 64), 256, 0, stream>>>(buf1, Wqkv, nullptr, nullptr, buf0, M, 1152, CC, 0);
    // 3. attention: buf0 -> buf1 (o, [M,384])
    attn_kernel<<<dim3(NN / QT, HEADS, BB), 256, 0, stream>>>(buf0, buf1);
    // 4. proj: out = x + o @ Wproj^T + bproj
    gemm_bt<<<dim3(CC / 64, M / 64), 256, 0, stream>>>(buf1, Wproj, bproj, x, out, M, CC, CC, 0);
    // 5. LN2: out -> buf1 (y)
    ln_kernel<<<M / 4, 256, 0, stream>>>(out, ln2_g, ln2_b, buf1);
    // 6. fc1: h1 = hardswish(y @ Wfc1^T + bfc1) -> buf0  [M,1536]
    gemm_bt<<<dim3(HID / 64, M / 64), 256, 0, stream>>>(buf1, Wfc1, bfc1, nullptr, buf0, M, HID, CC, 1);
    // 7. depthwise conv: buf0 -> buf1  [M,1536]
    dw_kernel<<<M, 256, 0, stream>>>(buf0, Wdw, bdw, buf1);
    // 8. fc2: out = out + h2 @ Wfc2^T + bfc2
    gemm_bt<<<dim3(CC / 64, M / 64), 256, 0, stream>>>(buf1, Wfc2, bfc2, out, out, M, CC, HID, 0);
}

// Round 2
// 1494.902 us; speedup vs baseline: 1.6361x; 1.6361x over previous
//
#include <hip/hip_runtime.h>
#include <hip/hip_bf16.h>
#include <math.h>

#define BB 16
#define NN 1024
#define CC 384
#define HEADS 4
#define HD 96
#define HID 1536
#define MROWS (BB*NN)

typedef __attribute__((ext_vector_type(8))) short bf16x8;
typedef __attribute__((ext_vector_type(4))) float f32x4;

__device__ __forceinline__ float hswish(float x) {
    float t = fminf(fmaxf(x + 3.0f, 0.0f), 6.0f);
    return x * t * (1.0f / 6.0f);
}

__device__ __forceinline__ ushort f2bf(float f) {
    union { float f; unsigned u; } v; v.f = f;
    unsigned r = v.u + 0x7fff + ((v.u >> 16) & 1);
    return (ushort)(r >> 16);
}

// ---------------- LayerNorm: one wave (64 lanes) per row of 384 ----------------
__global__ __launch_bounds__(256) void ln_kernel(
    const float* __restrict__ x, const float* __restrict__ g,
    const float* __restrict__ b, float* __restrict__ y)
{
    int row = blockIdx.x * 4 + (threadIdx.x >> 6);
    int lane = threadIdx.x & 63;
    const float* xr = x + (size_t)row * CC;
    float v[6];
    float s = 0.f;
#pragma unroll
    for (int j = 0; j < 6; ++j) { v[j] = xr[lane + 64 * j]; s += v[j]; }
#pragma unroll
    for (int off = 32; off; off >>= 1) s += __shfl_xor(s, off, 64);
    float mu = s * (1.0f / CC);
    float s2 = 0.f;
#pragma unroll
    for (int j = 0; j < 6; ++j) { float d = v[j] - mu; s2 += d * d; }
#pragma unroll
    for (int off = 32; off; off >>= 1) s2 += __shfl_xor(s2, off, 64);
    float rinv = rsqrtf(s2 * (1.0f / CC) + 1e-5f);
    float* yr = y + (size_t)row * CC;
#pragma unroll
    for (int j = 0; j < 6; ++j) {
        int c = lane + 64 * j;
        yr[c] = (v[j] - mu) * rinv * g[c] + b[c];
    }
}

// ---------------- GEMM: C[M,N] = A[M,K] @ B[N,K]^T (+bias, +act, +res) --------
__global__ __launch_bounds__(256) void gemm_bt(
    const float* __restrict__ A, const float* __restrict__ Bm,
    const float* __restrict__ bias, const float* __restrict__ res,
    float* __restrict__ C, int M, int N, int K, int act)
{
    __shared__ float As[16][65];
    __shared__ float Bs[16][65];
    int tid = threadIdx.x;
    int tx = tid & 15, ty = tid >> 4;
    int m0 = blockIdx.y * 64, n0 = blockIdx.x * 64;
    int lr = tid >> 2;
    int lk = (tid & 3) * 4;
    float acc[4][4] = {};
    for (int k0 = 0; k0 < K; k0 += 16) {
        float4 a4 = *(const float4*)(A + (size_t)(m0 + lr) * K + k0 + lk);
        float4 b4 = *(const float4*)(Bm + (size_t)(n0 + lr) * K + k0 + lk);
        __syncthreads();
        As[lk + 0][lr] = a4.x; As[lk + 1][lr] = a4.y;
        As[lk + 2][lr] = a4.z; As[lk + 3][lr] = a4.w;
        Bs[lk + 0][lr] = b4.x; Bs[lk + 1][lr] = b4.y;
        Bs[lk + 2][lr] = b4.z; Bs[lk + 3][lr] = b4.w;
        __syncthreads();
#pragma unroll
        for (int k = 0; k < 16; ++k) {
            float a[4], bv[4];
#pragma unroll
            for (int i = 0; i < 4; ++i) { a[i] = As[k][ty * 4 + i]; bv[i] = Bs[k][tx * 4 + i]; }
#pragma unroll
            for (int i = 0; i < 4; ++i)
#pragma unroll
                for (int j = 0; j < 4; ++j) acc[i][j] = fmaf(a[i], bv[j], acc[i][j]);
        }
    }
#pragma unroll
    for (int i = 0; i < 4; ++i) {
        int row = m0 + ty * 4 + i;
#pragma unroll
        for (int j = 0; j < 4; ++j) {
            int col = n0 + tx * 4 + j;
            float v = acc[i][j];
            if (bias) v += bias[col];
            if (act == 1) v = hswish(v);
            if (res) v += res[(size_t)row * N + col];
            C[(size_t)row * N + col] = v;
        }
    }
}

// ---------------- qkv f32 [M,1152] -> bf16 Qb,Kb [bh][N][96], Vt [bh][96][N] --
// scale (96^-0.5) folded into Q.
__global__ __launch_bounds__(256) void conv_qkv(
    const float* __restrict__ qkv, ushort* __restrict__ Qb,
    ushort* __restrict__ Kb, ushort* __restrict__ Vt)
{
    __shared__ ushort vt[HD][136];
    int n0 = blockIdx.x * 128;
    int h = blockIdx.y, b = blockIdx.z;
    int bh = b * HEADS + h;
    const float scale = 0.10206207261596577f;
    const float* base = qkv + (size_t)b * NN * 1152 + h * 288;
    for (int i = threadIdx.x; i < 128 * HD; i += 256) {
        int n = i / HD, d = i % HD;
        const float* row = base + (size_t)(n0 + n) * 1152;
        Qb[((size_t)bh * NN + n0 + n) * HD + d] = f2bf(row[d] * scale);
        Kb[((size_t)bh * NN + n0 + n) * HD + d] = f2bf(row[96 + d]);
        vt[d][n] = f2bf(row[192 + d]);
    }
    __syncthreads();
    for (int i = threadIdx.x; i < HD * 128; i += 256) {
        int d = i / 128, n = i % 128;
        Vt[((size_t)bh * HD + d) * NN + n0 + n] = vt[d][n];
    }
}

// ---------------- flash MFMA attention: block = (b, h, 64-query tile) ---------
#define KVT 64
#define KPAD 104
#define VPAD 72
#define PPAD 72

__global__ __launch_bounds__(256) void attn_mfma(
    const ushort* __restrict__ Qb, const ushort* __restrict__ Kb,
    const ushort* __restrict__ Vt, float* __restrict__ o)
{
    __shared__ ushort Klds[KVT][KPAD];
    __shared__ ushort Vlds[HD][VPAD];
    __shared__ ushort Plds[4][16][PPAD];
    int tid = threadIdx.x;
    int lane = tid & 63, w = tid >> 6;
    int g = lane >> 4, li = lane & 15;
    int q0 = blockIdx.x * 64;
    int h = blockIdx.y, b = blockIdx.z;
    int bh = b * HEADS + h;

    // Q fragments stay in registers for the whole kernel
    const ushort* qrow = Qb + ((size_t)bh * NN + q0 + w * 16 + li) * HD;
    bf16x8 qf[3];
#pragma unroll
    for (int s = 0; s < 3; ++s)
        qf[s] = *(const bf16x8*)(qrow + s * 32 + g * 8);

    f32x4 oacc[6];
#pragma unroll
    for (int dt = 0; dt < 6; ++dt) oacc[dt] = (f32x4){0.f, 0.f, 0.f, 0.f};
    float mrow[4], lrow[4];
#pragma unroll
    for (int r = 0; r < 4; ++r) { mrow[r] = -3e38f; lrow[r] = 0.f; }

    for (int t = 0; t < NN / KVT; ++t) {
        int n0 = t * KVT;
        __syncthreads();
        for (int i = tid; i < KVT * 12; i += 256) {
            int row = i / 12, ch = i % 12;
            *(bf16x8*)&Klds[row][ch * 8] =
                *(const bf16x8*)(Kb + ((size_t)bh * NN + n0 + row) * HD + ch * 8);
        }
        for (int i = tid; i < HD * 8; i += 256) {
            int d = i / 8, ch = i % 8;
            *(bf16x8*)&Vlds[d][ch * 8] =
                *(const bf16x8*)(Vt + ((size_t)bh * HD + d) * NN + n0 + ch * 8);
        }
        __syncthreads();

        // S = Q @ K^T  (16 q-rows x 64 kv per wave)
        f32x4 sacc[4];
#pragma unroll
        for (int c = 0; c < 4; ++c) sacc[c] = (f32x4){0.f, 0.f, 0.f, 0.f};
#pragma unroll
        for (int s = 0; s < 3; ++s)
#pragma unroll
            for (int c = 0; c < 4; ++c) {
                bf16x8 kf = *(const bf16x8*)&Klds[c * 16 + li][s * 32 + g * 8];
                sacc[c] = __builtin_amdgcn_mfma_f32_16x16x32_bf16(qf[s], kf, sacc[c], 0, 0, 0);
            }

        // online softmax; C-layout row=(g*4+r), col=c*16+li
        float corr[4];
#pragma unroll
        for (int r = 0; r < 4; ++r) {
            float mx = fmaxf(fmaxf(sacc[0][r], sacc[1][r]), fmaxf(sacc[2][r], sacc[3][r]));
#pragma unroll
            for (int off = 8; off; off >>= 1) mx = fmaxf(mx, __shfl_xor(mx, off, 64));
            float mnew = fmaxf(mrow[r], mx);
            corr[r] = __expf(mrow[r] - mnew);
            mrow[r] = mnew;
            float rs = 0.f;
#pragma unroll
            for (int c = 0; c < 4; ++c) {
                float p = __expf(sacc[c][r] - mnew);
                sacc[c][r] = p;
                rs += p;
            }
#pragma unroll
            for (int off = 8; off; off >>= 1) rs += __shfl_xor(rs, off, 64);
            lrow[r] = lrow[r] * corr[r] + rs;
        }
#pragma unroll
        for (int r = 0; r < 4; ++r) {
#pragma unroll
            for (int c = 0; c < 4; ++c)
                Plds[w][g * 4 + r][c * 16 + li] = f2bf(sacc[c][r]);
#pragma unroll
            for (int dt = 0; dt < 6; ++dt) oacc[dt][r] *= corr[r];
        }

        // O += P @ V
#pragma unroll
        for (int sub = 0; sub < 2; ++sub) {
            bf16x8 pf = *(const bf16x8*)&Plds[w][li][sub * 32 + g * 8];
#pragma unroll
            for (int dt = 0; dt < 6; ++dt) {
                bf16x8 vf = *(const bf16x8*)&Vlds[dt * 16 + li][sub * 32 + g * 8];
                oacc[dt] = __builtin_amdgcn_mfma_f32_16x16x32_bf16(pf, vf, oacc[dt], 0, 0, 0);
            }
        }
    }

    float inv[4];
#pragma unroll
    for (int r = 0; r < 4; ++r) inv[r] = 1.0f / lrow[r];
#pragma unroll
    for (int dt = 0; dt < 6; ++dt)
#pragma unroll
        for (int r = 0; r < 4; ++r) {
            int row = q0 + w * 16 + g * 4 + r;
            int col = h * HD + dt * 16 + li;
            o[(size_t)(b * NN + row) * CC + col] = oacc[dt][r] * inv[r];
        }
}

// ---------------- depthwise 3x3 conv over 32x32 spatial, 1536 channels -------
__global__ __launch_bounds__(256) void dw_kernel(
    const float* __restrict__ h1, const float* __restrict__ w,
    const float* __restrict__ bias, float* __restrict__ h2)
{
    int blk = blockIdx.x;
    int b = blk >> 10;
    int n = blk & 1023;
    int hh = n >> 5, ww = n & 31;
    const float* in = h1 + (size_t)b * NN * HID;
    float* outr = h2 + ((size_t)b * NN + n) * HID;
    for (int c = threadIdx.x; c < HID; c += 256) {
        float acc = bias[c];
#pragma unroll
        for (int ky = 0; ky < 3; ++ky) {
            int yy = hh + ky - 1;
            if (yy < 0 || yy > 31) continue;
#pragma unroll
            for (int kx = 0; kx < 3; ++kx) {
                int xx = ww + kx - 1;
                if (xx < 0 || xx > 31) continue;
                acc = fmaf(in[(size_t)(yy * 32 + xx) * HID + c], w[c * 9 + ky * 3 + kx], acc);
            }
        }
        outr[c] = hswish(acc);
    }
}

extern "C" void kernel_launch(void* const* d_in, const int* in_sizes, int n_in,
                              void* d_out, int out_size, void* d_ws, size_t ws_size,
                              hipStream_t stream) {
    const float* x     = (const float*)d_in[0];
    const float* ln1_g = (const float*)d_in[1];
    const float* ln1_b = (const float*)d_in[2];
    const float* Wqkv  = (const float*)d_in[3];
    const float* Wproj = (const float*)d_in[4];
    const float* bproj = (const float*)d_in[5];
    const float* ln2_g = (const float*)d_in[6];
    const float* ln2_b = (const float*)d_in[7];
    const float* Wfc1  = (const float*)d_in[8];
    const float* bfc1  = (const float*)d_in[9];
    const float* Wdw   = (const float*)d_in[10];
    const float* bdw   = (const float*)d_in[11];
    const float* Wfc2  = (const float*)d_in[12];
    const float* bfc2  = (const float*)d_in[13];
    float* out = (float*)d_out;

    float* fbuf0 = (float*)d_ws;                         // M x 1536 f32
    float* fbuf1 = fbuf0 + (size_t)MROWS * HID;          // M x 1536 f32
    ushort* Qb = (ushort*)(fbuf1 + (size_t)MROWS * CC);  // bf16 region after o
    ushort* Kb = Qb + (size_t)BB * HEADS * NN * HD;
    ushort* Vt = Kb + (size_t)BB * HEADS * NN * HD;

    const int M = MROWS;

    // 1. LN1: x -> fbuf1 (xn, [M,384])
    ln_kernel<<<M / 4, 256, 0, stream>>>(x, ln1_g, ln1_b, fbuf1);
    // 2. qkv = xn @ Wqkv^T -> fbuf0  [M,1152]
    gemm_bt<<<dim3(1152 / 64, M / 64), 256, 0, stream>>>(fbuf1, Wqkv, nullptr, nullptr, fbuf0, M, 1152, CC, 0);
    // 3. convert to bf16 Q(scaled)/K/V^T
    conv_qkv<<<dim3(NN / 128, HEADS, BB), 256, 0, stream>>>(fbuf0, Qb, Kb, Vt);
    // 4. attention -> fbuf1 (o, [M,384])
    attn_mfma<<<dim3(NN / 64, HEADS, BB), 256, 0, stream>>>(Qb, Kb, Vt, fbuf1);
    // 5. proj: out = x + o @ Wproj^T + bproj
    gemm_bt<<<dim3(CC / 64, M / 64), 256, 0, stream>>>(fbuf1, Wproj, bproj, x, out, M, CC, CC, 0);
    // 6. LN2: out -> fbuf1 (y, [M,384])
    ln_kernel<<<M / 4, 256, 0, stream>>>(out, ln2_g, ln2_b, fbuf1);
    // 7. fc1: h1 = hardswish(y @ Wfc1^T + bfc1) -> fbuf0  [M,1536]
    gemm_bt<<<dim3(HID / 64, M / 64), 256, 0, stream>>>(fbuf1, Wfc1, bfc1, nullptr, fbuf0, M, HID, CC, 1);
    // 8. depthwise conv: fbuf0 -> fbuf1  [M,1536]
    dw_kernel<<<M, 256, 0, stream>>>(fbuf0, Wdw, bdw, fbuf1);
    // 9. fc2: out = out + h2 @ Wfc2^T + bfc2
    gemm_bt<<<dim3(CC / 64, M / 64), 256, 0, stream>>>(fbuf1, Wfc2, bfc2, out, out, M, CC, HID, 0);
}

// Round 3
// 562.362 us; speedup vs baseline: 4.3491x; 2.6583x over previous
//
#include <hip/hip_runtime.h>
#include <hip/hip_bf16.h>
#include <math.h>

#define BB 16
#define NN 1024
#define CC 384
#define HEADS 4
#define HD 96
#define HID 1536
#define MROWS (BB*NN)

typedef __attribute__((ext_vector_type(8))) short bf16x8;
typedef __attribute__((ext_vector_type(4))) float f32x4;

__device__ __forceinline__ float hswish(float x) {
    float t = fminf(fmaxf(x + 3.0f, 0.0f), 6.0f);
    return x * t * (1.0f / 6.0f);
}

__device__ __forceinline__ ushort f2bf(float f) {
    union { float f; unsigned u; } v; v.f = f;
    unsigned r = v.u + 0x7fff + ((v.u >> 16) & 1);
    return (ushort)(r >> 16);
}

__device__ __forceinline__ float bf2f(ushort u) {
    union { unsigned u; float f; } v; v.u = ((unsigned)u) << 16;
    return v.f;
}

// ---------------- weight fp32 -> bf16 ----------------
__global__ __launch_bounds__(256) void wconv(const float* __restrict__ s,
                                             ushort* __restrict__ d, int n) {
    int i = blockIdx.x * 256 + threadIdx.x;
    if (i < n) d[i] = f2bf(s[i]);
}

// Wqkv with 96^-0.5 folded into the Q rows ((row%288)<96)
__global__ __launch_bounds__(256) void wconv_qkv(const float* __restrict__ s,
                                                 ushort* __restrict__ d) {
    int i = blockIdx.x * 256 + threadIdx.x;
    if (i < 1152 * 384) {
        int row = i / 384;
        float v = s[i];
        if ((row % 288) < 96) v *= 0.10206207261596577f;
        d[i] = f2bf(v);
    }
}

// ---------------- LayerNorm: one wave per row of 384, bf16 out ----------------
__global__ __launch_bounds__(256) void ln_kernel(
    const float* __restrict__ x, const float* __restrict__ g,
    const float* __restrict__ b, ushort* __restrict__ y)
{
    int row = blockIdx.x * 4 + (threadIdx.x >> 6);
    int lane = threadIdx.x & 63;
    const float* xr = x + (size_t)row * CC;
    float v[6];
    float s = 0.f;
#pragma unroll
    for (int j = 0; j < 6; ++j) { v[j] = xr[lane + 64 * j]; s += v[j]; }
#pragma unroll
    for (int off = 32; off; off >>= 1) s += __shfl_xor(s, off, 64);
    float mu = s * (1.0f / CC);
    float s2 = 0.f;
#pragma unroll
    for (int j = 0; j < 6; ++j) { float d = v[j] - mu; s2 += d * d; }
#pragma unroll
    for (int off = 32; off; off >>= 1) s2 += __shfl_xor(s2, off, 64);
    float rinv = rsqrtf(s2 * (1.0f / CC) + 1e-5f);
    ushort* yr = y + (size_t)row * CC;
#pragma unroll
    for (int j = 0; j < 6; ++j) {
        int c = lane + 64 * j;
        yr[c] = f2bf((v[j] - mu) * rinv * g[c] + b[c]);
    }
}

// ------------- bf16 MFMA GEMM: C[M,N] = A[M,K] @ B[N,K]^T (+bias/act/res) -----
// 128x128 tile, 256 threads = 4 waves (2x2 of 64x64), BK=64, XOR-swizzled LDS.
__global__ __launch_bounds__(256) void gemm_mfma(
    const ushort* __restrict__ A, const ushort* __restrict__ B,
    const float* __restrict__ bias, const float* __restrict__ res,
    float* __restrict__ Cf, ushort* __restrict__ Cb,
    int M, int N, int K, int act)
{
    __shared__ ushort As[128][64];
    __shared__ ushort Bs[128][64];
    int tid = threadIdx.x;
    int lane = tid & 63, w = tid >> 6;
    int wr = w >> 1, wc = w & 1;
    int g = lane >> 4, li = lane & 15;
    int m0 = blockIdx.y * 128, n0 = blockIdx.x * 128;

    int srow = tid >> 3;        // 0..31 row within 32-row staging chunk
    int sc = tid & 7;           // 16B chunk within 128B row
    int swz = sc ^ (srow & 7);  // swizzled LDS chunk

    f32x4 acc[4][4];
#pragma unroll
    for (int m = 0; m < 4; ++m)
#pragma unroll
        for (int n = 0; n < 4; ++n) acc[m][n] = (f32x4){0.f, 0.f, 0.f, 0.f};

    for (int k0 = 0; k0 < K; k0 += 64) {
        __syncthreads();
#pragma unroll
        for (int j = 0; j < 4; ++j) {
            int row = j * 32 + srow;
            *(bf16x8*)&As[row][swz * 8] =
                *(const bf16x8*)(A + (size_t)(m0 + row) * K + k0 + sc * 8);
            *(bf16x8*)&Bs[row][swz * 8] =
                *(const bf16x8*)(B + (size_t)(n0 + row) * K + k0 + sc * 8);
        }
        __syncthreads();
#pragma unroll
        for (int s = 0; s < 2; ++s) {
            bf16x8 af[4], bfr[4];
#pragma unroll
            for (int m = 0; m < 4; ++m) {
                int row = wr * 64 + m * 16 + li;
                af[m] = *(const bf16x8*)&As[row][((s * 4 + g) ^ (row & 7)) * 8];
            }
#pragma unroll
            for (int n = 0; n < 4; ++n) {
                int row = wc * 64 + n * 16 + li;
                bfr[n] = *(const bf16x8*)&Bs[row][((s * 4 + g) ^ (row & 7)) * 8];
            }
#pragma unroll
            for (int m = 0; m < 4; ++m)
#pragma unroll
                for (int n = 0; n < 4; ++n)
                    acc[m][n] = __builtin_amdgcn_mfma_f32_16x16x32_bf16(
                        af[m], bfr[n], acc[m][n], 0, 0, 0);
        }
    }

#pragma unroll
    for (int m = 0; m < 4; ++m)
#pragma unroll
        for (int n = 0; n < 4; ++n) {
            int col = n0 + wc * 64 + n * 16 + li;
            float bv = bias ? bias[col] : 0.f;
#pragma unroll
            for (int r = 0; r < 4; ++r) {
                int row = m0 + wr * 64 + m * 16 + g * 4 + r;
                float v = acc[m][n][r] + bv;
                if (act == 1) v = hswish(v);
                if (res) v += res[(size_t)row * N + col];
                if (Cb) Cb[(size_t)row * N + col] = f2bf(v);
                else    Cf[(size_t)row * N + col] = v;
            }
        }
}

// ------------- qkv bf16 [M,1152] -> Qb,Kb [bh][N][96], Vt [bh][96][N] ---------
__global__ __launch_bounds__(256) void conv_qkv(
    const ushort* __restrict__ qkv, ushort* __restrict__ Qb,
    ushort* __restrict__ Kb, ushort* __restrict__ Vt)
{
    __shared__ ushort vt[HD][136];
    int n0 = blockIdx.x * 128;
    int h = blockIdx.y, b = blockIdx.z;
    int bh = b * HEADS + h;
    const ushort* base = qkv + (size_t)b * NN * 1152 + h * 288;
    for (int i = threadIdx.x; i < 128 * HD; i += 256) {
        int n = i / HD, d = i % HD;
        const ushort* row = base + (size_t)(n0 + n) * 1152;
        Qb[((size_t)bh * NN + n0 + n) * HD + d] = row[d];
        Kb[((size_t)bh * NN + n0 + n) * HD + d] = row[96 + d];
        vt[d][n] = row[192 + d];
    }
    __syncthreads();
    for (int i = threadIdx.x; i < HD * 128; i += 256) {
        int d = i / 128, n = i % 128;
        Vt[((size_t)bh * HD + d) * NN + n0 + n] = vt[d][n];
    }
}

// ---------------- flash MFMA attention: block = (b, h, 64-query tile) ---------
#define KVT 64
#define KPAD 104
#define VPAD 72
#define PPAD 72

__global__ __launch_bounds__(256) void attn_mfma(
    const ushort* __restrict__ Qb, const ushort* __restrict__ Kb,
    const ushort* __restrict__ Vt, ushort* __restrict__ o)
{
    __shared__ ushort Klds[KVT][KPAD];
    __shared__ ushort Vlds[HD][VPAD];
    __shared__ ushort Plds[4][16][PPAD];
    int tid = threadIdx.x;
    int lane = tid & 63, w = tid >> 6;
    int g = lane >> 4, li = lane & 15;
    int q0 = blockIdx.x * 64;
    int h = blockIdx.y, b = blockIdx.z;
    int bh = b * HEADS + h;

    const ushort* qrow = Qb + ((size_t)bh * NN + q0 + w * 16 + li) * HD;
    bf16x8 qf[3];
#pragma unroll
    for (int s = 0; s < 3; ++s)
        qf[s] = *(const bf16x8*)(qrow + s * 32 + g * 8);

    f32x4 oacc[6];
#pragma unroll
    for (int dt = 0; dt < 6; ++dt) oacc[dt] = (f32x4){0.f, 0.f, 0.f, 0.f};
    float mrow[4], lrow[4];
#pragma unroll
    for (int r = 0; r < 4; ++r) { mrow[r] = -3e38f; lrow[r] = 0.f; }

    for (int t = 0; t < NN / KVT; ++t) {
        int n0 = t * KVT;
        __syncthreads();
        for (int i = tid; i < KVT * 12; i += 256) {
            int row = i / 12, ch = i % 12;
            *(bf16x8*)&Klds[row][ch * 8] =
                *(const bf16x8*)(Kb + ((size_t)bh * NN + n0 + row) * HD + ch * 8);
        }
        for (int i = tid; i < HD * 8; i += 256) {
            int d = i / 8, ch = i % 8;
            *(bf16x8*)&Vlds[d][ch * 8] =
                *(const bf16x8*)(Vt + ((size_t)bh * HD + d) * NN + n0 + ch * 8);
        }
        __syncthreads();

        f32x4 sacc[4];
#pragma unroll
        for (int c = 0; c < 4; ++c) sacc[c] = (f32x4){0.f, 0.f, 0.f, 0.f};
#pragma unroll
        for (int s = 0; s < 3; ++s)
#pragma unroll
            for (int c = 0; c < 4; ++c) {
                bf16x8 kf = *(const bf16x8*)&Klds[c * 16 + li][s * 32 + g * 8];
                sacc[c] = __builtin_amdgcn_mfma_f32_16x16x32_bf16(qf[s], kf, sacc[c], 0, 0, 0);
            }

        float corr[4];
#pragma unroll
        for (int r = 0; r < 4; ++r) {
            float mx = fmaxf(fmaxf(sacc[0][r], sacc[1][r]), fmaxf(sacc[2][r], sacc[3][r]));
#pragma unroll
            for (int off = 8; off; off >>= 1) mx = fmaxf(mx, __shfl_xor(mx, off, 64));
            float mnew = fmaxf(mrow[r], mx);
            corr[r] = __expf(mrow[r] - mnew);
            mrow[r] = mnew;
            float rs = 0.f;
#pragma unroll
            for (int c = 0; c < 4; ++c) {
                float p = __expf(sacc[c][r] - mnew);
                sacc[c][r] = p;
                rs += p;
            }
#pragma unroll
            for (int off = 8; off; off >>= 1) rs += __shfl_xor(rs, off, 64);
            lrow[r] = lrow[r] * corr[r] + rs;
        }
#pragma unroll
        for (int r = 0; r < 4; ++r) {
#pragma unroll
            for (int c = 0; c < 4; ++c)
                Plds[w][g * 4 + r][c * 16 + li] = f2bf(sacc[c][r]);
#pragma unroll
            for (int dt = 0; dt < 6; ++dt) oacc[dt][r] *= corr[r];
        }

#pragma unroll
        for (int sub = 0; sub < 2; ++sub) {
            bf16x8 pf = *(const bf16x8*)&Plds[w][li][sub * 32 + g * 8];
#pragma unroll
            for (int dt = 0; dt < 6; ++dt) {
                bf16x8 vf = *(const bf16x8*)&Vlds[dt * 16 + li][sub * 32 + g * 8];
                oacc[dt] = __builtin_amdgcn_mfma_f32_16x16x32_bf16(pf, vf, oacc[dt], 0, 0, 0);
            }
        }
    }

    float inv[4];
#pragma unroll
    for (int r = 0; r < 4; ++r) inv[r] = 1.0f / lrow[r];
#pragma unroll
    for (int dt = 0; dt < 6; ++dt)
#pragma unroll
        for (int r = 0; r < 4; ++r) {
            int row = q0 + w * 16 + g * 4 + r;
            int col = h * HD + dt * 16 + li;
            o[(size_t)(b * NN + row) * CC + col] = f2bf(oacc[dt][r] * inv[r]);
        }
}

// -------- depthwise 3x3 conv, bf16 in/out, 2 channels per thread --------------
__global__ __launch_bounds__(256) void dw_kernel(
    const ushort* __restrict__ h1, const float* __restrict__ w,
    const float* __restrict__ bias, ushort* __restrict__ h2)
{
    int blk = blockIdx.x;
    int b = blk >> 10;
    int n = blk & 1023;
    int hh = n >> 5, ww = n & 31;
    const ushort* in = h1 + (size_t)b * NN * HID;
    ushort* outr = h2 + ((size_t)b * NN + n) * HID;
    for (int cp = threadIdx.x; cp < HID / 2; cp += 256) {
        int c0 = cp * 2;
        float a0 = bias[c0], a1 = bias[c0 + 1];
#pragma unroll
        for (int ky = 0; ky < 3; ++ky) {
            int yy = hh + ky - 1;
            if (yy < 0 || yy > 31) continue;
#pragma unroll
            for (int kx = 0; kx < 3; ++kx) {
                int xx = ww + kx - 1;
                if (xx < 0 || xx > 31) continue;
                ushort2 u = *(const ushort2*)&in[(size_t)(yy * 32 + xx) * HID + c0];
                int k = ky * 3 + kx;
                a0 = fmaf(bf2f(u.x), w[c0 * 9 + k], a0);
                a1 = fmaf(bf2f(u.y), w[(c0 + 1) * 9 + k], a1);
            }
        }
        ushort2 ov;
        ov.x = f2bf(hswish(a0));
        ov.y = f2bf(hswish(a1));
        *(ushort2*)&outr[c0] = ov;
    }
}

extern "C" void kernel_launch(void* const* d_in, const int* in_sizes, int n_in,
                              void* d_out, int out_size, void* d_ws, size_t ws_size,
                              hipStream_t stream) {
    const float* x     = (const float*)d_in[0];
    const float* ln1_g = (const float*)d_in[1];
    const float* ln1_b = (const float*)d_in[2];
    const float* Wqkv  = (const float*)d_in[3];
    const float* Wproj = (const float*)d_in[4];
    const float* bproj = (const float*)d_in[5];
    const float* ln2_g = (const float*)d_in[6];
    const float* ln2_b = (const float*)d_in[7];
    const float* Wfc1  = (const float*)d_in[8];
    const float* bfc1  = (const float*)d_in[9];
    const float* Wdw   = (const float*)d_in[10];
    const float* bdw   = (const float*)d_in[11];
    const float* Wfc2  = (const float*)d_in[12];
    const float* bfc2  = (const float*)d_in[13];
    float* out = (float*)d_out;

    const int M = MROWS;
    ushort* abuf = (ushort*)d_ws;              // M x 384 (xn / y)
    ushort* qkvb = abuf + (size_t)M * 384;     // M x 1152
    ushort* Qb   = qkvb + (size_t)M * 1152;    // M x 384
    ushort* Kb   = Qb   + (size_t)M * 384;
    ushort* Vt   = Kb   + (size_t)M * 384;
    ushort* obuf = Vt   + (size_t)M * 384;     // M x 384
    ushort* h1   = obuf + (size_t)M * 384;     // M x 1536
    ushort* h2   = h1   + (size_t)M * 1536;    // M x 1536
    ushort* wq   = h2   + (size_t)M * 1536;    // 1152x384
    ushort* wp   = wq   + 1152 * 384;          // 384x384
    ushort* w1   = wp   + 384 * 384;           // 1536x384
    ushort* w2   = w1   + 1536 * 384;          // 384x1536

    // weights -> bf16 (scale folded into Wqkv Q-rows)
    wconv_qkv<<<(1152 * 384 + 255) / 256, 256, 0, stream>>>(Wqkv, wq);
    wconv<<<(384 * 384 + 255) / 256, 256, 0, stream>>>(Wproj, wp, 384 * 384);
    wconv<<<(1536 * 384 + 255) / 256, 256, 0, stream>>>(Wfc1, w1, 1536 * 384);
    wconv<<<(384 * 1536 + 255) / 256, 256, 0, stream>>>(Wfc2, w2, 384 * 1536);

    // 1. LN1: x -> abuf (bf16)
    ln_kernel<<<M / 4, 256, 0, stream>>>(x, ln1_g, ln1_b, abuf);
    // 2. qkv = xn @ Wqkv^T -> qkvb (bf16)
    gemm_mfma<<<dim3(1152 / 128, M / 128), 256, 0, stream>>>(
        abuf, wq, nullptr, nullptr, nullptr, qkvb, M, 1152, CC, 0);
    // 3. split/transpose
    conv_qkv<<<dim3(NN / 128, HEADS, BB), 256, 0, stream>>>(qkvb, Qb, Kb, Vt);
    // 4. attention -> obuf (bf16)
    attn_mfma<<<dim3(NN / 64, HEADS, BB), 256, 0, stream>>>(Qb, Kb, Vt, obuf);
    // 5. proj: out = x + o @ Wproj^T + bproj   (f32)
    gemm_mfma<<<dim3(CC / 128, M / 128), 256, 0, stream>>>(
        obuf, wp, bproj, x, out, nullptr, M, CC, CC, 0);
    // 6. LN2: out -> abuf (bf16)
    ln_kernel<<<M / 4, 256, 0, stream>>>(out, ln2_g, ln2_b, abuf);
    // 7. fc1: h1 = hardswish(y @ Wfc1^T + bfc1) (bf16)
    gemm_mfma<<<dim3(HID / 128, M / 128), 256, 0, stream>>>(
        abuf, w1, bfc1, nullptr, nullptr, h1, M, HID, CC, 1);
    // 8. depthwise conv (bf16 -> bf16)
    dw_kernel<<<M, 256, 0, stream>>>(h1, Wdw, bdw, h2);
    // 9. fc2: out = out + h2 @ Wfc2^T + bfc2   (f32)
    gemm_mfma<<<dim3(CC / 128, M / 128), 256, 0, stream>>>(
        h2, w2, bfc2, out, out, nullptr, M, CC, HID, 0);
}

// Round 4
// 333.899 us; speedup vs baseline: 7.3249x; 1.6842x over previous
//
#include <hip/hip_runtime.h>
#include <hip/hip_bf16.h>
#include <math.h>

#define BB 16
#define NN 1024
#define CC 384
#define HEADS 4
#define HD 96
#define HID 1536
#define MROWS (BB*NN)

typedef __attribute__((ext_vector_type(8))) short bf16x8;
typedef __attribute__((ext_vector_type(4))) float f32x4;

__device__ __forceinline__ float hswish(float x) {
    float t = fminf(fmaxf(x + 3.0f, 0.0f), 6.0f);
    return x * t * (1.0f / 6.0f);
}

__device__ __forceinline__ ushort f2bf(float f) {
    union { float f; unsigned u; } v; v.f = f;
    unsigned r = v.u + 0x7fff + ((v.u >> 16) & 1);
    return (ushort)(r >> 16);
}

__device__ __forceinline__ float bf2f(ushort u) {
    union { unsigned u; float f; } v; v.u = ((unsigned)u) << 16;
    return v.f;
}

// ---------------- weight fp32 -> bf16 ----------------
__global__ __launch_bounds__(256) void wconv(const float* __restrict__ s,
                                             ushort* __restrict__ d, int n) {
    int i = blockIdx.x * 256 + threadIdx.x;
    if (i < n) d[i] = f2bf(s[i]);
}

// Wqkv with 96^-0.5 folded into the Q rows ((row%288)<96)
__global__ __launch_bounds__(256) void wconv_qkv(const float* __restrict__ s,
                                                 ushort* __restrict__ d) {
    int i = blockIdx.x * 256 + threadIdx.x;
    if (i < 1152 * 384) {
        int row = i / 384;
        float v = s[i];
        if ((row % 288) < 96) v *= 0.10206207261596577f;
        d[i] = f2bf(v);
    }
}

// ---------------- LayerNorm: one wave per row of 384, bf16 out ----------------
__global__ __launch_bounds__(256) void ln_kernel(
    const float* __restrict__ x, const float* __restrict__ g,
    const float* __restrict__ b, ushort* __restrict__ y)
{
    int row = blockIdx.x * 4 + (threadIdx.x >> 6);
    int lane = threadIdx.x & 63;
    const float* xr = x + (size_t)row * CC;
    float v[6];
    float s = 0.f;
#pragma unroll
    for (int j = 0; j < 6; ++j) { v[j] = xr[lane + 64 * j]; s += v[j]; }
#pragma unroll
    for (int off = 32; off; off >>= 1) s += __shfl_xor(s, off, 64);
    float mu = s * (1.0f / CC);
    float s2 = 0.f;
#pragma unroll
    for (int j = 0; j < 6; ++j) { float d = v[j] - mu; s2 += d * d; }
#pragma unroll
    for (int off = 32; off; off >>= 1) s2 += __shfl_xor(s2, off, 64);
    float rinv = rsqrtf(s2 * (1.0f / CC) + 1e-5f);
    ushort* yr = y + (size_t)row * CC;
#pragma unroll
    for (int j = 0; j < 6; ++j) {
        int c = lane + 64 * j;
        yr[c] = f2bf((v[j] - mu) * rinv * g[c] + b[c]);
    }
}

// ------------- bf16 MFMA GEMM: C[M,N] = A[M,K] @ B[N,K]^T (+bias/act/res) -----
__global__ __launch_bounds__(256) void gemm_mfma(
    const ushort* __restrict__ A, const ushort* __restrict__ B,
    const float* __restrict__ bias, const float* __restrict__ res,
    float* __restrict__ Cf, ushort* __restrict__ Cb,
    int M, int N, int K, int act)
{
    __shared__ ushort As[128][64];
    __shared__ ushort Bs[128][64];
    int tid = threadIdx.x;
    int lane = tid & 63, w = tid >> 6;
    int wr = w >> 1, wc = w & 1;
    int g = lane >> 4, li = lane & 15;
    int m0 = blockIdx.y * 128, n0 = blockIdx.x * 128;

    int srow = tid >> 3;
    int sc = tid & 7;
    int swz = sc ^ (srow & 7);

    f32x4 acc[4][4];
#pragma unroll
    for (int m = 0; m < 4; ++m)
#pragma unroll
        for (int n = 0; n < 4; ++n) acc[m][n] = (f32x4){0.f, 0.f, 0.f, 0.f};

    for (int k0 = 0; k0 < K; k0 += 64) {
        __syncthreads();
#pragma unroll
        for (int j = 0; j < 4; ++j) {
            int row = j * 32 + srow;
            *(bf16x8*)&As[row][swz * 8] =
                *(const bf16x8*)(A + (size_t)(m0 + row) * K + k0 + sc * 8);
            *(bf16x8*)&Bs[row][swz * 8] =
                *(const bf16x8*)(B + (size_t)(n0 + row) * K + k0 + sc * 8);
        }
        __syncthreads();
#pragma unroll
        for (int s = 0; s < 2; ++s) {
            bf16x8 af[4], bfr[4];
#pragma unroll
            for (int m = 0; m < 4; ++m) {
                int row = wr * 64 + m * 16 + li;
                af[m] = *(const bf16x8*)&As[row][((s * 4 + g) ^ (row & 7)) * 8];
            }
#pragma unroll
            for (int n = 0; n < 4; ++n) {
                int row = wc * 64 + n * 16 + li;
                bfr[n] = *(const bf16x8*)&Bs[row][((s * 4 + g) ^ (row & 7)) * 8];
            }
#pragma unroll
            for (int m = 0; m < 4; ++m)
#pragma unroll
                for (int n = 0; n < 4; ++n)
                    acc[m][n] = __builtin_amdgcn_mfma_f32_16x16x32_bf16(
                        af[m], bfr[n], acc[m][n], 0, 0, 0);
        }
    }

#pragma unroll
    for (int m = 0; m < 4; ++m)
#pragma unroll
        for (int n = 0; n < 4; ++n) {
            int col = n0 + wc * 64 + n * 16 + li;
            float bv = bias ? bias[col] : 0.f;
#pragma unroll
            for (int r = 0; r < 4; ++r) {
                int row = m0 + wr * 64 + m * 16 + g * 4 + r;
                float v = acc[m][n][r] + bv;
                if (act == 1) v = hswish(v);
                if (res) v += res[(size_t)row * N + col];
                if (Cb) Cb[(size_t)row * N + col] = f2bf(v);
                else    Cf[(size_t)row * N + col] = v;
            }
        }
}

// ------------- qkv bf16 [M,1152] -> Qb,Kb [bh][N][96], Vt [bh][96][N] ---------
__global__ __launch_bounds__(256) void conv_qkv(
    const ushort* __restrict__ qkv, ushort* __restrict__ Qb,
    ushort* __restrict__ Kb, ushort* __restrict__ Vt)
{
    __shared__ ushort vt[HD][136];
    int n0 = blockIdx.x * 128;
    int h = blockIdx.y, b = blockIdx.z;
    int bh = b * HEADS + h;
    const ushort* base = qkv + (size_t)b * NN * 1152 + h * 288;
    for (int i = threadIdx.x; i < 128 * HD; i += 256) {
        int n = i / HD, d = i % HD;
        const ushort* row = base + (size_t)(n0 + n) * 1152;
        Qb[((size_t)bh * NN + n0 + n) * HD + d] = row[d];
        Kb[((size_t)bh * NN + n0 + n) * HD + d] = row[96 + d];
        vt[d][n] = row[192 + d];
    }
    __syncthreads();
    for (int i = threadIdx.x; i < HD * 128; i += 256) {
        int d = i / 128, n = i % 128;
        Vt[((size_t)bh * HD + d) * NN + n0 + n] = vt[d][n];
    }
}

// ---------------- flash MFMA attention: block = (b, h, 64-query tile) ---------
#define KVT 64
#define KPAD 104
#define VPAD 72
#define PPAD 72

__global__ __launch_bounds__(256) void attn_mfma(
    const ushort* __restrict__ Qb, const ushort* __restrict__ Kb,
    const ushort* __restrict__ Vt, ushort* __restrict__ o)
{
    __shared__ ushort Klds[KVT][KPAD];
    __shared__ ushort Vlds[HD][VPAD];
    __shared__ ushort Plds[4][16][PPAD];
    int tid = threadIdx.x;
    int lane = tid & 63, w = tid >> 6;
    int g = lane >> 4, li = lane & 15;
    int q0 = blockIdx.x * 64;
    int h = blockIdx.y, b = blockIdx.z;
    int bh = b * HEADS + h;

    const ushort* qrow = Qb + ((size_t)bh * NN + q0 + w * 16 + li) * HD;
    bf16x8 qf[3];
#pragma unroll
    for (int s = 0; s < 3; ++s)
        qf[s] = *(const bf16x8*)(qrow + s * 32 + g * 8);

    f32x4 oacc[6];
#pragma unroll
    for (int dt = 0; dt < 6; ++dt) oacc[dt] = (f32x4){0.f, 0.f, 0.f, 0.f};
    float mrow[4], lrow[4];
#pragma unroll
    for (int r = 0; r < 4; ++r) { mrow[r] = -3e38f; lrow[r] = 0.f; }

    for (int t = 0; t < NN / KVT; ++t) {
        int n0 = t * KVT;
        __syncthreads();
        for (int i = tid; i < KVT * 12; i += 256) {
            int row = i / 12, ch = i % 12;
            *(bf16x8*)&Klds[row][ch * 8] =
                *(const bf16x8*)(Kb + ((size_t)bh * NN + n0 + row) * HD + ch * 8);
        }
        for (int i = tid; i < HD * 8; i += 256) {
            int d = i / 8, ch = i % 8;
            *(bf16x8*)&Vlds[d][ch * 8] =
                *(const bf16x8*)(Vt + ((size_t)bh * HD + d) * NN + n0 + ch * 8);
        }
        __syncthreads();

        f32x4 sacc[4];
#pragma unroll
        for (int c = 0; c < 4; ++c) sacc[c] = (f32x4){0.f, 0.f, 0.f, 0.f};
#pragma unroll
        for (int s = 0; s < 3; ++s)
#pragma unroll
            for (int c = 0; c < 4; ++c) {
                bf16x8 kf = *(const bf16x8*)&Klds[c * 16 + li][s * 32 + g * 8];
                sacc[c] = __builtin_amdgcn_mfma_f32_16x16x32_bf16(qf[s], kf, sacc[c], 0, 0, 0);
            }

        float corr[4];
#pragma unroll
        for (int r = 0; r < 4; ++r) {
            float mx = fmaxf(fmaxf(sacc[0][r], sacc[1][r]), fmaxf(sacc[2][r], sacc[3][r]));
#pragma unroll
            for (int off = 8; off; off >>= 1) mx = fmaxf(mx, __shfl_xor(mx, off, 64));
            float mnew = fmaxf(mrow[r], mx);
            corr[r] = __expf(mrow[r] - mnew);
            mrow[r] = mnew;
            float rs = 0.f;
#pragma unroll
            for (int c = 0; c < 4; ++c) {
                float p = __expf(sacc[c][r] - mnew);
                sacc[c][r] = p;
                rs += p;
            }
#pragma unroll
            for (int off = 8; off; off >>= 1) rs += __shfl_xor(rs, off, 64);
            lrow[r] = lrow[r] * corr[r] + rs;
        }
#pragma unroll
        for (int r = 0; r < 4; ++r) {
#pragma unroll
            for (int c = 0; c < 4; ++c)
                Plds[w][g * 4 + r][c * 16 + li] = f2bf(sacc[c][r]);
#pragma unroll
            for (int dt = 0; dt < 6; ++dt) oacc[dt][r] *= corr[r];
        }

#pragma unroll
        for (int sub = 0; sub < 2; ++sub) {
            bf16x8 pf = *(const bf16x8*)&Plds[w][li][sub * 32 + g * 8];
#pragma unroll
            for (int dt = 0; dt < 6; ++dt) {
                bf16x8 vf = *(const bf16x8*)&Vlds[dt * 16 + li][sub * 32 + g * 8];
                oacc[dt] = __builtin_amdgcn_mfma_f32_16x16x32_bf16(pf, vf, oacc[dt], 0, 0, 0);
            }
        }
    }

    float inv[4];
#pragma unroll
    for (int r = 0; r < 4; ++r) inv[r] = 1.0f / lrow[r];
#pragma unroll
    for (int dt = 0; dt < 6; ++dt)
#pragma unroll
        for (int r = 0; r < 4; ++r) {
            int row = q0 + w * 16 + g * 4 + r;
            int col = h * HD + dt * 16 + li;
            o[(size_t)(b * NN + row) * CC + col] = f2bf(oacc[dt][r] * inv[r]);
        }
}

// -------- depthwise 3x3: rolling-window column sweep, 2 ch x 1 col per thread -
// grid: (HID/128, 32/4, BB); thread: cp=tid&63 -> 2 channels, xw=tid>>6 -> col
__global__ __launch_bounds__(256) void dw_kernel(
    const ushort* __restrict__ h1, const float* __restrict__ w,
    const float* __restrict__ bias, ushort* __restrict__ h2)
{
    int tid = threadIdx.x;
    int c0 = blockIdx.x * 128 + (tid & 63) * 2;
    int x = blockIdx.y * 4 + (tid >> 6);
    int b = blockIdx.z;
    const ushort* base = h1 + (size_t)b * NN * HID + c0;
    ushort* obase = h2 + (size_t)b * NN * HID + c0;

    float wA[9], wB[9];
#pragma unroll
    for (int k = 0; k < 9; ++k) {
        wA[k] = w[c0 * 9 + k];
        wB[k] = w[(c0 + 1) * 9 + k];
    }
    float bA = bias[c0], bB = bias[c0 + 1];

    bool xm = (x > 0), xp = (x < 31);

    // window rows: m (y-1), c (y), n (y+1); cols 0..2 = x-1,x,x+1; 2 channels
    float m0a = 0, m0b = 0, m1a = 0, m1b = 0, m2a = 0, m2b = 0;
    float c0a = 0, c0b = 0, c1a = 0, c1b = 0, c2a = 0, c2b = 0;

    // load row 0 into "c"
    {
        if (xm) { ushort2 u = *(const ushort2*)&base[(size_t)(x - 1) * HID]; c0a = bf2f(u.x); c0b = bf2f(u.y); }
        { ushort2 u = *(const ushort2*)&base[(size_t)x * HID]; c1a = bf2f(u.x); c1b = bf2f(u.y); }
        if (xp) { ushort2 u = *(const ushort2*)&base[(size_t)(x + 1) * HID]; c2a = bf2f(u.x); c2b = bf2f(u.y); }
    }

#pragma unroll
    for (int y = 0; y < 32; ++y) {
        float n0a = 0, n0b = 0, n1a = 0, n1b = 0, n2a = 0, n2b = 0;
        if (y < 31) {
            const ushort* rp = base + (size_t)((y + 1) * 32 + x) * HID;
            if (xm) { ushort2 u = *(const ushort2*)(rp - HID); n0a = bf2f(u.x); n0b = bf2f(u.y); }
            { ushort2 u = *(const ushort2*)rp; n1a = bf2f(u.x); n1b = bf2f(u.y); }
            if (xp) { ushort2 u = *(const ushort2*)(rp + HID); n2a = bf2f(u.x); n2b = bf2f(u.y); }
        }
        float aA = bA, aB = bB;
        aA = fmaf(m0a, wA[0], aA); aB = fmaf(m0b, wB[0], aB);
        aA = fmaf(m1a, wA[1], aA); aB = fmaf(m1b, wB[1], aB);
        aA = fmaf(m2a, wA[2], aA); aB = fmaf(m2b, wB[2], aB);
        aA = fmaf(c0a, wA[3], aA); aB = fmaf(c0b, wB[3], aB);
        aA = fmaf(c1a, wA[4], aA); aB = fmaf(c1b, wB[4], aB);
        aA = fmaf(c2a, wA[5], aA); aB = fmaf(c2b, wB[5], aB);
        aA = fmaf(n0a, wA[6], aA); aB = fmaf(n0b, wB[6], aB);
        aA = fmaf(n1a, wA[7], aA); aB = fmaf(n1b, wB[7], aB);
        aA = fmaf(n2a, wA[8], aA); aB = fmaf(n2b, wB[8], aB);
        ushort2 ov;
        ov.x = f2bf(hswish(aA));
        ov.y = f2bf(hswish(aB));
        *(ushort2*)&obase[(size_t)(y * 32 + x) * HID] = ov;
        // roll window
        m0a = c0a; m0b = c0b; m1a = c1a; m1b = c1b; m2a = c2a; m2b = c2b;
        c0a = n0a; c0b = n0b; c1a = n1a; c1b = n1b; c2a = n2a; c2b = n2b;
    }
}

extern "C" void kernel_launch(void* const* d_in, const int* in_sizes, int n_in,
                              void* d_out, int out_size, void* d_ws, size_t ws_size,
                              hipStream_t stream) {
    const float* x     = (const float*)d_in[0];
    const float* ln1_g = (const float*)d_in[1];
    const float* ln1_b = (const float*)d_in[2];
    const float* Wqkv  = (const float*)d_in[3];
    const float* Wproj = (const float*)d_in[4];
    const float* bproj = (const float*)d_in[5];
    const float* ln2_g = (const float*)d_in[6];
    const float* ln2_b = (const float*)d_in[7];
    const float* Wfc1  = (const float*)d_in[8];
    const float* bfc1  = (const float*)d_in[9];
    const float* Wdw   = (const float*)d_in[10];
    const float* bdw   = (const float*)d_in[11];
    const float* Wfc2  = (const float*)d_in[12];
    const float* bfc2  = (const float*)d_in[13];
    float* out = (float*)d_out;

    const int M = MROWS;
    ushort* abuf = (ushort*)d_ws;              // M x 384 (xn / y)
    ushort* qkvb = abuf + (size_t)M * 384;     // M x 1152
    ushort* Qb   = qkvb + (size_t)M * 1152;    // M x 384
    ushort* Kb   = Qb   + (size_t)M * 384;
    ushort* Vt   = Kb   + (size_t)M * 384;
    ushort* obuf = Vt   + (size_t)M * 384;     // M x 384
    ushort* h1   = obuf + (size_t)M * 384;     // M x 1536
    ushort* h2   = h1   + (size_t)M * 1536;    // M x 1536
    ushort* wq   = h2   + (size_t)M * 1536;    // 1152x384
    ushort* wp   = wq   + 1152 * 384;          // 384x384
    ushort* w1   = wp   + 384 * 384;           // 1536x384
    ushort* w2   = w1   + 1536 * 384;          // 384x1536

    wconv_qkv<<<(1152 * 384 + 255) / 256, 256, 0, stream>>>(Wqkv, wq);
    wconv<<<(384 * 384 + 255) / 256, 256, 0, stream>>>(Wproj, wp, 384 * 384);
    wconv<<<(1536 * 384 + 255) / 256, 256, 0, stream>>>(Wfc1, w1, 1536 * 384);
    wconv<<<(384 * 1536 + 255) / 256, 256, 0, stream>>>(Wfc2, w2, 384 * 1536);

    // 1. LN1: x -> abuf (bf16)
    ln_kernel<<<M / 4, 256, 0, stream>>>(x, ln1_g, ln1_b, abuf);
    // 2. qkv = xn @ Wqkv^T -> qkvb (bf16)
    gemm_mfma<<<dim3(1152 / 128, M / 128), 256, 0, stream>>>(
        abuf, wq, nullptr, nullptr, nullptr, qkvb, M, 1152, CC, 0);
    // 3. split/transpose
    conv_qkv<<<dim3(NN / 128, HEADS, BB), 256, 0, stream>>>(qkvb, Qb, Kb, Vt);
    // 4. attention -> obuf (bf16)
    attn_mfma<<<dim3(NN / 64, HEADS, BB), 256, 0, stream>>>(Qb, Kb, Vt, obuf);
    // 5. proj: out = x + o @ Wproj^T + bproj   (f32)
    gemm_mfma<<<dim3(CC / 128, M / 128), 256, 0, stream>>>(
        obuf, wp, bproj, x, out, nullptr, M, CC, CC, 0);
    // 6. LN2: out -> abuf (bf16)
    ln_kernel<<<M / 4, 256, 0, stream>>>(out, ln2_g, ln2_b, abuf);
    // 7. fc1: h1 = hardswish(y @ Wfc1^T + bfc1) (bf16)
    gemm_mfma<<<dim3(HID / 128, M / 128), 256, 0, stream>>>(
        abuf, w1, bfc1, nullptr, nullptr, h1, M, HID, CC, 1);
    // 8. depthwise conv (bf16 -> bf16)
    dw_kernel<<<dim3(HID / 128, 8, BB), 256, 0, stream>>>(h1, Wdw, bdw, h2);
    // 9. fc2: out = out + h2 @ Wfc2^T + bfc2   (f32)
    gemm_mfma<<<dim3(CC / 128, M / 128), 256, 0, stream>>>(
        h2, w2, bfc2, out, out, nullptr, M, CC, HID, 0);
}

// Round 5
// 333.325 us; speedup vs baseline: 7.3375x; 1.0017x over previous
//
#include <hip/hip_runtime.h>
#include <hip/hip_bf16.h>
#include <math.h>

#define BB 16
#define NN 1024
#define CC 384
#define HEADS 4
#define HD 96
#define HID 1536
#define MROWS (BB*NN)

typedef __attribute__((ext_vector_type(8))) short bf16x8;
typedef __attribute__((ext_vector_type(4))) float f32x4;

__device__ __forceinline__ float hswish(float x) {
    float t = fminf(fmaxf(x + 3.0f, 0.0f), 6.0f);
    return x * t * (1.0f / 6.0f);
}

__device__ __forceinline__ ushort f2bf(float f) {
    union { float f; unsigned u; } v; v.f = f;
    unsigned r = v.u + 0x7fff + ((v.u >> 16) & 1);
    return (ushort)(r >> 16);
}

__device__ __forceinline__ float bf2f(ushort u) {
    union { unsigned u; float f; } v; v.u = ((unsigned)u) << 16;
    return v.f;
}

// ---------------- weight fp32 -> bf16 ----------------
__global__ __launch_bounds__(256) void wconv(const float* __restrict__ s,
                                             ushort* __restrict__ d, int n) {
    int i = blockIdx.x * 256 + threadIdx.x;
    if (i < n) d[i] = f2bf(s[i]);
}

__global__ __launch_bounds__(256) void wconv_qkv(const float* __restrict__ s,
                                                 ushort* __restrict__ d) {
    int i = blockIdx.x * 256 + threadIdx.x;
    if (i < 1152 * 384) {
        int row = i / 384;
        float v = s[i];
        if ((row % 288) < 96) v *= 0.10206207261596577f;
        d[i] = f2bf(v);
    }
}

// ---------------- LayerNorm: one wave per row of 384, bf16 out ----------------
__global__ __launch_bounds__(256) void ln_kernel(
    const float* __restrict__ x, const float* __restrict__ g,
    const float* __restrict__ b, ushort* __restrict__ y)
{
    int row = blockIdx.x * 4 + (threadIdx.x >> 6);
    int lane = threadIdx.x & 63;
    const float* xr = x + (size_t)row * CC;
    float v[6];
    float s = 0.f;
#pragma unroll
    for (int j = 0; j < 6; ++j) { v[j] = xr[lane + 64 * j]; s += v[j]; }
#pragma unroll
    for (int off = 32; off; off >>= 1) s += __shfl_xor(s, off, 64);
    float mu = s * (1.0f / CC);
    float s2 = 0.f;
#pragma unroll
    for (int j = 0; j < 6; ++j) { float d = v[j] - mu; s2 += d * d; }
#pragma unroll
    for (int off = 32; off; off >>= 1) s2 += __shfl_xor(s2, off, 64);
    float rinv = rsqrtf(s2 * (1.0f / CC) + 1e-5f);
    ushort* yr = y + (size_t)row * CC;
#pragma unroll
    for (int j = 0; j < 6; ++j) {
        int c = lane + 64 * j;
        yr[c] = f2bf((v[j] - mu) * rinv * g[c] + b[c]);
    }
}

// ------------- bf16 MFMA GEMM: C[M,N] = A[M,K] @ B[N,K]^T (+bias/act/res) -----
// 128xBN tile, 256 threads = 4 waves (2x2), BK=64, XOR-swizzled LDS.
template<int BN>
__global__ __launch_bounds__(256) void gemm_mfma(
    const ushort* __restrict__ A, const ushort* __restrict__ B,
    const float* __restrict__ bias, const float* __restrict__ res,
    float* __restrict__ Cf, ushort* __restrict__ Cb,
    int M, int N, int K, int act)
{
    constexpr int NF = BN / 32;          // 16-col frags per wave
    __shared__ ushort As[128][64];
    __shared__ ushort Bs[BN][64];
    int tid = threadIdx.x;
    int lane = tid & 63, w = tid >> 6;
    int wr = w >> 1, wc = w & 1;
    int g = lane >> 4, li = lane & 15;
    int m0 = blockIdx.y * 128, n0 = blockIdx.x * BN;

    int srow = tid >> 3;
    int sc = tid & 7;
    int swz = sc ^ (srow & 7);

    f32x4 acc[4][NF];
#pragma unroll
    for (int m = 0; m < 4; ++m)
#pragma unroll
        for (int n = 0; n < NF; ++n) acc[m][n] = (f32x4){0.f, 0.f, 0.f, 0.f};

    for (int k0 = 0; k0 < K; k0 += 64) {
        __syncthreads();
#pragma unroll
        for (int j = 0; j < 4; ++j) {
            int row = j * 32 + srow;
            *(bf16x8*)&As[row][swz * 8] =
                *(const bf16x8*)(A + (size_t)(m0 + row) * K + k0 + sc * 8);
        }
#pragma unroll
        for (int j = 0; j < BN / 32; ++j) {
            int row = j * 32 + srow;
            *(bf16x8*)&Bs[row][swz * 8] =
                *(const bf16x8*)(B + (size_t)(n0 + row) * K + k0 + sc * 8);
        }
        __syncthreads();
#pragma unroll
        for (int s = 0; s < 2; ++s) {
            bf16x8 af[4], bfr[NF];
#pragma unroll
            for (int m = 0; m < 4; ++m) {
                int row = wr * 64 + m * 16 + li;
                af[m] = *(const bf16x8*)&As[row][((s * 4 + g) ^ (row & 7)) * 8];
            }
#pragma unroll
            for (int n = 0; n < NF; ++n) {
                int row = wc * (BN / 2) + n * 16 + li;
                bfr[n] = *(const bf16x8*)&Bs[row][((s * 4 + g) ^ (row & 7)) * 8];
            }
            __builtin_amdgcn_s_setprio(1);
#pragma unroll
            for (int m = 0; m < 4; ++m)
#pragma unroll
                for (int n = 0; n < NF; ++n)
                    acc[m][n] = __builtin_amdgcn_mfma_f32_16x16x32_bf16(
                        af[m], bfr[n], acc[m][n], 0, 0, 0);
            __builtin_amdgcn_s_setprio(0);
        }
    }

#pragma unroll
    for (int m = 0; m < 4; ++m)
#pragma unroll
        for (int n = 0; n < NF; ++n) {
            int col = n0 + wc * (BN / 2) + n * 16 + li;
            float bv = bias ? bias[col] : 0.f;
#pragma unroll
            for (int r = 0; r < 4; ++r) {
                int row = m0 + wr * 64 + m * 16 + g * 4 + r;
                float v = acc[m][n][r] + bv;
                if (act == 1) v = hswish(v);
                if (res) v += res[(size_t)row * N + col];
                if (Cb) Cb[(size_t)row * N + col] = f2bf(v);
                else    Cf[(size_t)row * N + col] = v;
            }
        }
}

// ------------- qkv bf16 [M,1152] -> Qb,Kb [bh][N][96], Vt [bh][96][N] ---------
__global__ __launch_bounds__(256) void conv_qkv(
    const ushort* __restrict__ qkv, ushort* __restrict__ Qb,
    ushort* __restrict__ Kb, ushort* __restrict__ Vt)
{
    __shared__ ushort vt[HD][136];
    int n0 = blockIdx.x * 128;
    int h = blockIdx.y, b = blockIdx.z;
    int bh = b * HEADS + h;
    const ushort* base = qkv + (size_t)b * NN * 1152 + h * 288;
    for (int i = threadIdx.x; i < 128 * HD; i += 256) {
        int n = i / HD, d = i % HD;
        const ushort* row = base + (size_t)(n0 + n) * 1152;
        Qb[((size_t)bh * NN + n0 + n) * HD + d] = row[d];
        Kb[((size_t)bh * NN + n0 + n) * HD + d] = row[96 + d];
        vt[d][n] = row[192 + d];
    }
    __syncthreads();
    for (int i = threadIdx.x; i < HD * 128; i += 256) {
        int d = i / 128, n = i % 128;
        Vt[((size_t)bh * HD + d) * NN + n0 + n] = vt[d][n];
    }
}

// ---------------- flash MFMA attention ----------------------------------------
// 1-D grid of 512: bid = qt*64 + bh  (bh in low bits -> same bh on same XCD).
// Block handles 128 q-rows; wave w owns rows [w*32, w*32+32) as 2 subtiles.
#define KVT 64
#define KPAD 104
#define VPAD 72
#define PPAD 72

__global__ __launch_bounds__(256) void attn_mfma(
    const ushort* __restrict__ Qb, const ushort* __restrict__ Kb,
    const ushort* __restrict__ Vt, ushort* __restrict__ o)
{
    __shared__ ushort Klds[KVT][KPAD];
    __shared__ ushort Vlds[HD][VPAD];
    __shared__ ushort Plds[4][16][PPAD];
    int tid = threadIdx.x;
    int lane = tid & 63, w = tid >> 6;
    int g = lane >> 4, li = lane & 15;
    int bid = blockIdx.x;
    int qt = bid >> 6, bh = bid & 63;
    int q0 = qt * 128;
    int b = bh >> 2, h = bh & 3;

    bf16x8 qf[2][3];
#pragma unroll
    for (int u = 0; u < 2; ++u) {
        const ushort* qrow = Qb + ((size_t)bh * NN + q0 + w * 32 + u * 16 + li) * HD;
#pragma unroll
        for (int s = 0; s < 3; ++s)
            qf[u][s] = *(const bf16x8*)(qrow + s * 32 + g * 8);
    }

    f32x4 oacc[2][6];
    float mrow[2][4], lrow[2][4];
#pragma unroll
    for (int u = 0; u < 2; ++u) {
#pragma unroll
        for (int dt = 0; dt < 6; ++dt) oacc[u][dt] = (f32x4){0.f, 0.f, 0.f, 0.f};
#pragma unroll
        for (int r = 0; r < 4; ++r) { mrow[u][r] = -3e38f; lrow[u][r] = 0.f; }
    }

    for (int t = 0; t < NN / KVT; ++t) {
        int n0 = t * KVT;
        __syncthreads();
        for (int i = tid; i < KVT * 12; i += 256) {
            int row = i / 12, ch = i % 12;
            *(bf16x8*)&Klds[row][ch * 8] =
                *(const bf16x8*)(Kb + ((size_t)bh * NN + n0 + row) * HD + ch * 8);
        }
        for (int i = tid; i < HD * 8; i += 256) {
            int d = i / 8, ch = i % 8;
            *(bf16x8*)&Vlds[d][ch * 8] =
                *(const bf16x8*)(Vt + ((size_t)bh * HD + d) * NN + n0 + ch * 8);
        }
        __syncthreads();

#pragma unroll
        for (int u = 0; u < 2; ++u) {
            f32x4 sacc[4];
#pragma unroll
            for (int c = 0; c < 4; ++c) sacc[c] = (f32x4){0.f, 0.f, 0.f, 0.f};
            __builtin_amdgcn_s_setprio(1);
#pragma unroll
            for (int s = 0; s < 3; ++s)
#pragma unroll
                for (int c = 0; c < 4; ++c) {
                    bf16x8 kf = *(const bf16x8*)&Klds[c * 16 + li][s * 32 + g * 8];
                    sacc[c] = __builtin_amdgcn_mfma_f32_16x16x32_bf16(qf[u][s], kf, sacc[c], 0, 0, 0);
                }
            __builtin_amdgcn_s_setprio(0);

            float mx[4];
#pragma unroll
            for (int r = 0; r < 4; ++r) {
                float m = fmaxf(fmaxf(sacc[0][r], sacc[1][r]), fmaxf(sacc[2][r], sacc[3][r]));
#pragma unroll
                for (int off = 8; off; off >>= 1) m = fmaxf(m, __shfl_xor(m, off, 64));
                mx[r] = m;
            }
            int small = 1;
#pragma unroll
            for (int r = 0; r < 4; ++r) small &= (mx[r] <= mrow[u][r] + 8.f);

            if (__all(small)) {
                // fast path: keep old max, no rescale
#pragma unroll
                for (int r = 0; r < 4; ++r) {
                    float rs = 0.f;
#pragma unroll
                    for (int c = 0; c < 4; ++c) {
                        float p = __expf(sacc[c][r] - mrow[u][r]);
                        sacc[c][r] = p;
                        rs += p;
                    }
#pragma unroll
                    for (int off = 8; off; off >>= 1) rs += __shfl_xor(rs, off, 64);
                    lrow[u][r] += rs;
                }
            } else {
#pragma unroll
                for (int r = 0; r < 4; ++r) {
                    float mnew = fmaxf(mrow[u][r], mx[r]);
                    float corr = __expf(mrow[u][r] - mnew);
                    mrow[u][r] = mnew;
                    float rs = 0.f;
#pragma unroll
                    for (int c = 0; c < 4; ++c) {
                        float p = __expf(sacc[c][r] - mnew);
                        sacc[c][r] = p;
                        rs += p;
                    }
#pragma unroll
                    for (int off = 8; off; off >>= 1) rs += __shfl_xor(rs, off, 64);
                    lrow[u][r] = lrow[u][r] * corr + rs;
#pragma unroll
                    for (int dt = 0; dt < 6; ++dt) oacc[u][dt][r] *= corr;
                }
            }

#pragma unroll
            for (int r = 0; r < 4; ++r)
#pragma unroll
                for (int c = 0; c < 4; ++c)
                    Plds[w][g * 4 + r][c * 16 + li] = f2bf(sacc[c][r]);

            __builtin_amdgcn_s_setprio(1);
#pragma unroll
            for (int sub = 0; sub < 2; ++sub) {
                bf16x8 pf = *(const bf16x8*)&Plds[w][li][sub * 32 + g * 8];
#pragma unroll
                for (int dt = 0; dt < 6; ++dt) {
                    bf16x8 vf = *(const bf16x8*)&Vlds[dt * 16 + li][sub * 32 + g * 8];
                    oacc[u][dt] = __builtin_amdgcn_mfma_f32_16x16x32_bf16(pf, vf, oacc[u][dt], 0, 0, 0);
                }
            }
            __builtin_amdgcn_s_setprio(0);
        }
    }

#pragma unroll
    for (int u = 0; u < 2; ++u) {
        float inv[4];
#pragma unroll
        for (int r = 0; r < 4; ++r) inv[r] = 1.0f / lrow[u][r];
#pragma unroll
        for (int dt = 0; dt < 6; ++dt)
#pragma unroll
            for (int r = 0; r < 4; ++r) {
                int row = q0 + w * 32 + u * 16 + g * 4 + r;
                int col = h * HD + dt * 16 + li;
                o[(size_t)(b * NN + row) * CC + col] = f2bf(oacc[u][dt][r] * inv[r]);
            }
    }
}

// -------- depthwise 3x3: rolling-window column sweep, 2 ch x 1 col per thread -
__global__ __launch_bounds__(256) void dw_kernel(
    const ushort* __restrict__ h1, const float* __restrict__ w,
    const float* __restrict__ bias, ushort* __restrict__ h2)
{
    int tid = threadIdx.x;
    int c0 = blockIdx.x * 128 + (tid & 63) * 2;
    int x = blockIdx.y * 4 + (tid >> 6);
    int b = blockIdx.z;
    const ushort* base = h1 + (size_t)b * NN * HID + c0;
    ushort* obase = h2 + (size_t)b * NN * HID + c0;

    float wA[9], wB[9];
#pragma unroll
    for (int k = 0; k < 9; ++k) {
        wA[k] = w[c0 * 9 + k];
        wB[k] = w[(c0 + 1) * 9 + k];
    }
    float bA = bias[c0], bB = bias[c0 + 1];

    bool xm = (x > 0), xp = (x < 31);

    float m0a = 0, m0b = 0, m1a = 0, m1b = 0, m2a = 0, m2b = 0;
    float c0a = 0, c0b = 0, c1a = 0, c1b = 0, c2a = 0, c2b = 0;

    {
        if (xm) { ushort2 u = *(const ushort2*)&base[(size_t)(x - 1) * HID]; c0a = bf2f(u.x); c0b = bf2f(u.y); }
        { ushort2 u = *(const ushort2*)&base[(size_t)x * HID]; c1a = bf2f(u.x); c1b = bf2f(u.y); }
        if (xp) { ushort2 u = *(const ushort2*)&base[(size_t)(x + 1) * HID]; c2a = bf2f(u.x); c2b = bf2f(u.y); }
    }

#pragma unroll
    for (int y = 0; y < 32; ++y) {
        float n0a = 0, n0b = 0, n1a = 0, n1b = 0, n2a = 0, n2b = 0;
        if (y < 31) {
            const ushort* rp = base + (size_t)((y + 1) * 32 + x) * HID;
            if (xm) { ushort2 u = *(const ushort2*)(rp - HID); n0a = bf2f(u.x); n0b = bf2f(u.y); }
            { ushort2 u = *(const ushort2*)rp; n1a = bf2f(u.x); n1b = bf2f(u.y); }
            if (xp) { ushort2 u = *(const ushort2*)(rp + HID); n2a = bf2f(u.x); n2b = bf2f(u.y); }
        }
        float aA = bA, aB = bB;
        aA = fmaf(m0a, wA[0], aA); aB = fmaf(m0b, wB[0], aB);
        aA = fmaf(m1a, wA[1], aA); aB = fmaf(m1b, wB[1], aB);
        aA = fmaf(m2a, wA[2], aA); aB = fmaf(m2b, wB[2], aB);
        aA = fmaf(c0a, wA[3], aA); aB = fmaf(c0b, wB[3], aB);
        aA = fmaf(c1a, wA[4], aA); aB = fmaf(c1b, wB[4], aB);
        aA = fmaf(c2a, wA[5], aA); aB = fmaf(c2b, wB[5], aB);
        aA = fmaf(n0a, wA[6], aA); aB = fmaf(n0b, wB[6], aB);
        aA = fmaf(n1a, wA[7], aA); aB = fmaf(n1b, wB[7], aB);
        aA = fmaf(n2a, wA[8], aA); aB = fmaf(n2b, wB[8], aB);
        ushort2 ov;
        ov.x = f2bf(hswish(aA));
        ov.y = f2bf(hswish(aB));
        *(ushort2*)&obase[(size_t)(y * 32 + x) * HID] = ov;
        m0a = c0a; m0b = c0b; m1a = c1a; m1b = c1b; m2a = c2a; m2b = c2b;
        c0a = n0a; c0b = n0b; c1a = n1a; c1b = n1b; c2a = n2a; c2b = n2b;
    }
}

extern "C" void kernel_launch(void* const* d_in, const int* in_sizes, int n_in,
                              void* d_out, int out_size, void* d_ws, size_t ws_size,
                              hipStream_t stream) {
    const float* x     = (const float*)d_in[0];
    const float* ln1_g = (const float*)d_in[1];
    const float* ln1_b = (const float*)d_in[2];
    const float* Wqkv  = (const float*)d_in[3];
    const float* Wproj = (const float*)d_in[4];
    const float* bproj = (const float*)d_in[5];
    const float* ln2_g = (const float*)d_in[6];
    const float* ln2_b = (const float*)d_in[7];
    const float* Wfc1  = (const float*)d_in[8];
    const float* bfc1  = (const float*)d_in[9];
    const float* Wdw   = (const float*)d_in[10];
    const float* bdw   = (const float*)d_in[11];
    const float* Wfc2  = (const float*)d_in[12];
    const float* bfc2  = (const float*)d_in[13];
    float* out = (float*)d_out;

    const int M = MROWS;
    ushort* abuf = (ushort*)d_ws;              // M x 384
    ushort* qkvb = abuf + (size_t)M * 384;     // M x 1152
    ushort* Qb   = qkvb + (size_t)M * 1152;    // M x 384
    ushort* Kb   = Qb   + (size_t)M * 384;
    ushort* Vt   = Kb   + (size_t)M * 384;
    ushort* obuf = Vt   + (size_t)M * 384;     // M x 384
    ushort* h1   = obuf + (size_t)M * 384;     // M x 1536
    ushort* h2   = h1   + (size_t)M * 1536;    // M x 1536
    ushort* wq   = h2   + (size_t)M * 1536;    // 1152x384
    ushort* wp   = wq   + 1152 * 384;          // 384x384
    ushort* w1   = wp   + 384 * 384;           // 1536x384
    ushort* w2   = w1   + 1536 * 384;          // 384x1536

    wconv_qkv<<<(1152 * 384 + 255) / 256, 256, 0, stream>>>(Wqkv, wq);
    wconv<<<(384 * 384 + 255) / 256, 256, 0, stream>>>(Wproj, wp, 384 * 384);
    wconv<<<(1536 * 384 + 255) / 256, 256, 0, stream>>>(Wfc1, w1, 1536 * 384);
    wconv<<<(384 * 1536 + 255) / 256, 256, 0, stream>>>(Wfc2, w2, 384 * 1536);

    // 1. LN1
    ln_kernel<<<M / 4, 256, 0, stream>>>(x, ln1_g, ln1_b, abuf);
    // 2. qkv GEMM
    gemm_mfma<128><<<dim3(1152 / 128, M / 128), 256, 0, stream>>>(
        abuf, wq, nullptr, nullptr, nullptr, qkvb, M, 1152, CC, 0);
    // 3. split/transpose
    conv_qkv<<<dim3(NN / 128, HEADS, BB), 256, 0, stream>>>(qkvb, Qb, Kb, Vt);
    // 4. attention (512 blocks, bh in low 6 bits for XCD locality)
    attn_mfma<<<512, 256, 0, stream>>>(Qb, Kb, Vt, obuf);
    // 5. proj (+residual, f32 out)
    gemm_mfma<64><<<dim3(CC / 64, M / 128), 256, 0, stream>>>(
        obuf, wp, bproj, x, out, nullptr, M, CC, CC, 0);
    // 6. LN2
    ln_kernel<<<M / 4, 256, 0, stream>>>(out, ln2_g, ln2_b, abuf);
    // 7. fc1 (+hardswish, bf16 out)
    gemm_mfma<128><<<dim3(HID / 128, M / 128), 256, 0, stream>>>(
        abuf, w1, bfc1, nullptr, nullptr, h1, M, HID, CC, 1);
    // 8. depthwise conv
    dw_kernel<<<dim3(HID / 128, 8, BB), 256, 0, stream>>>(h1, Wdw, bdw, h2);
    // 9. fc2 (+residual, f32 out)
    gemm_mfma<64><<<dim3(CC / 64, M / 128), 256, 0, stream>>>(
        h2, w2, bfc2, out, out, nullptr, M, CC, HID, 0);
}